// Round 1
// baseline (52.685 us; speedup 1.0000x reference)
//
#include <hip/hip_runtime.h>

#define DI __device__ __forceinline__

constexpr int BATCH = 256;
constexpr int INF   = 4096;   // in_features
constexpr int NGRP  = 1024;   // INF/4
constexpr int MOUT  = 4096;   // out_features

constexpr int BM = 128, BN = 128, BK = 64;
constexpr int KSPLIT = 4;
constexpr int KRANGE = INF / KSPLIT;  // 1024
constexpr int NIT    = KRANGE / BK;   // 16

using bf16x8 = __attribute__((ext_vector_type(8))) short;
using f32x4  = __attribute__((ext_vector_type(4))) float;

// D4 half-codebook, stored as 2x the actual values (int8); actual = v * 0.5
__device__ __constant__ signed char D4_I8[512] = {
     0, 0, 0, 0,  -4, 0, 0, 0,  -2,-2,-2,-2,  -2,-2,-2, 0,  -2,-2,-2, 2,  -2,-2, 0,-2,  -2,-2, 0, 0,  -2,-2, 0, 2,
    -2,-2, 2,-2,  -2,-2, 2, 0,  -2,-2, 2, 2,  -2, 0,-2,-2,  -2, 0,-2, 0,  -2, 0,-2, 2,  -2, 0, 0,-2,  -2, 0, 0, 0,
    -2, 0, 0, 2,  -2, 0, 2,-2,  -2, 0, 2, 0,  -2, 0, 2, 2,  -2, 2,-2,-2,  -2, 2,-2, 0,  -2, 2,-2, 2,  -2, 2, 0,-2,
    -2, 2, 0, 0,  -2, 2, 0, 2,  -2, 2, 2,-2,  -2, 2, 2, 0,  -2, 2, 2, 2,   0,-4, 0, 0,   0,-2,-2,-2,   0,-2,-2, 0,
     0,-2,-2, 2,   0,-2, 0,-2,   0,-2, 0, 0,   0,-2, 0, 2,   0,-2, 2,-2,   0,-2, 2, 0,   0,-2, 2, 2,   0, 0,-4, 0,
     0, 0,-2,-2,   0, 0,-2, 0,   0, 0,-2, 2,   0, 0, 0,-4,   0, 0, 0,-2,
    -3,-1,-3,-1,  -3,-1,-3, 1,  -3,-1,-1,-3,  -3,-1,-1,-1,  -3,-1,-1, 1,  -3,-1,-1, 3,  -3,-1, 1,-3,  -3,-1, 1,-1,
    -3,-1, 1, 1,  -3,-1, 1, 3,  -3,-1, 3,-1,  -3,-1, 3, 1,  -3, 1,-3,-1,  -3, 1,-3, 1,  -3, 1,-1,-3,  -3, 1,-1,-1,
    -3, 1,-1, 1,  -3, 1,-1, 3,  -3, 1, 1,-3,  -3, 1, 1,-1,  -3, 1, 1, 1,  -3, 1, 1, 3,  -3, 1, 3,-1,  -3, 1, 3, 1,
    -3, 3,-1,-1,  -3, 3, 1,-1,  -3, 3, 1, 1,  -1,-3,-3,-1,  -1,-3,-3, 1,  -1,-3,-1,-3,  -1,-3,-1,-1,  -1,-3,-1, 1,
    -1,-3,-1, 3,  -1,-3, 1,-3,  -1,-3, 1,-1,  -1,-3, 1, 1,  -1,-3, 1, 3,  -1,-3, 3,-1,  -1,-3, 3, 1,  -1,-1,-3,-3,
    -1,-1,-3,-1,  -1,-1,-3, 1,  -1,-1,-3, 3,  -1,-1,-1,-3,  -1,-1,-1,-1,  -1,-1,-1, 1,  -1,-1,-1, 3,  -1,-1, 1,-3,
    -1,-1, 1,-1,  -1,-1, 1, 1,  -1,-1, 1, 3,  -1,-1, 3,-3,  -1,-1, 3,-1,  -1,-1, 3, 1,  -1,-1, 3, 3,  -1, 1,-3,-3,
    -1, 1,-3,-1,  -1, 1,-3, 1,  -1, 1,-3, 3,  -1, 1,-1,-3,  -1, 1,-1,-1,  -1, 1,-1, 1,  -1, 1,-1, 3,  -1, 1, 1,-3,
    -1, 1, 1,-1,  -1, 1, 1, 1,  -1, 1, 1, 3,  -1, 1, 3,-3,  -1, 1, 3,-1,  -1, 1, 3, 1,  -1, 1, 3, 3,  -1, 3,-3,-1,
    -1, 3,-3, 1,  -1, 3,-1,-3,  -1, 3,-1,-1,  -1, 3,-1, 1,  -1, 3,-1, 3,  -1, 3, 1,-3,  -1, 3, 1,-1,  -1, 3, 1, 1,
    -1, 3, 1, 3,  -1, 3, 3,-1,  -1, 3, 3, 1
};

DI unsigned short f2bf(float f) {  // f32 -> bf16 bits, round-to-nearest-even
  unsigned int u = __float_as_uint(f);
  u += 0x7fffu + ((u >> 16) & 1u);
  return (unsigned short)(u >> 16);
}

// Fused: zero d_out + build Xs = input * scaleW_DSC * Qscales (bf16) into d_ws.
__global__ __launch_bounds__(256) void prep_kernel(
    const float* __restrict__ inp, const float* __restrict__ sw,
    const float* __restrict__ qs, unsigned short* __restrict__ xs,
    float* __restrict__ out) {
  int i = blockIdx.x * 256 + threadIdx.x;      // group-of-4 index, 262144 total
  reinterpret_cast<float4*>(out)[i] = make_float4(0.f, 0.f, 0.f, 0.f);
  int g = i & (NGRP - 1);
  float4 v = reinterpret_cast<const float4*>(inp)[i];
  float4 s = reinterpret_cast<const float4*>(sw)[g];
  float  q = qs[g];
  ushort4 o;
  o.x = f2bf(v.x * s.x * q);
  o.y = f2bf(v.y * s.y * q);
  o.z = f2bf(v.z * s.z * q);
  o.w = f2bf(v.w * s.w * q);
  reinterpret_cast<ushort4*>(xs)[i] = o;
}

// Fused dequant-GEMM: C[256,4096] += Xs[256,4096] . W^T, W rows dequantized
// from Qidxs via a 256-entry (sign-folded) bf16x4 codebook table in LDS.
__global__ __launch_bounds__(256, 2) void gemm_kernel(
    const unsigned short* __restrict__ xs, const int* __restrict__ qidx,
    float* __restrict__ out) {
  __shared__ unsigned long long tbl[256];          // 2 KB
  __shared__ unsigned short WT[2][BN * BK];        // 2 x 16 KB, XOR-swizzled rows

  const int tid  = threadIdx.x;
  const int lane = tid & 63;
  const int wave = tid >> 6;
  const int bid  = blockIdx.x;
  const int nt = bid & 31;
  const int mt = (bid >> 5) & 1;
  const int ks = bid >> 6;                 // 0..KSPLIT-1
  const int m0 = mt * BM, n0 = nt * BN, k0 = ks * KRANGE;

  // ---- build signed codebook table: tbl[i] = 4 packed bf16, tbl[i+128] = -tbl[i]
  {
    int r = tid & 127, sg = tid >> 7;
    unsigned long long v = 0;
#pragma unroll
    for (int j = 0; j < 4; ++j) {
      float f = (float)D4_I8[r * 4 + j] * 0.5f;
      unsigned int b = __float_as_uint(f) ^ (sg ? 0x80000000u : 0u);
      v |= (unsigned long long)(b >> 16) << (16 * j);
    }
    tbl[tid] = v;
  }

  // ---- dequant staging mapping: thread -> (W row, 8-group half)
  const int drow = tid >> 1;               // 0..127
  const int dh   = tid & 1;                // 0/1
  const int* gq0 = qidx + (size_t)(n0 + drow) * NGRP + (k0 >> 2) + dh * 8;

  int4 qa, qb;                             // in-flight index registers
  auto dq_load = [&](int it) {
    const int* gq = gq0 + it * 16;
    qa = *reinterpret_cast<const int4*>(gq);
    qb = *reinterpret_cast<const int4*>(gq + 4);
  };
  auto dq_write = [&](int buf) {
    char* wb = (char*)(&WT[buf][0]) + drow * 128;
    const unsigned int swz = (unsigned)(drow & 7) << 4;
    const int q[8] = {qa.x, qa.y, qa.z, qa.w, qb.x, qb.y, qb.z, qb.w};
#pragma unroll
    for (int j = 0; j < 8; ++j) {
      unsigned long long c = tbl[q[j] & 255];
      *reinterpret_cast<unsigned long long*>(
          wb + ((unsigned)(dh * 64 + j * 8) ^ swz)) = c;
    }
  };

  // ---- compute-side mapping
  const int wm = wave >> 1, wn = wave & 1;       // 2x2 waves, 64x64 each
  const int l15 = lane & 15, l4 = lane >> 4;
  const unsigned short* xb =
      xs + (size_t)(m0 + wm * 64 + l15) * INF + k0 + l4 * 8;
  const unsigned int bswz = (unsigned)(l15 & 7) << 4;

  f32x4 acc[4][4] = {};

  // ---- prologue: stage tile 0
  dq_load(0);
  __syncthreads();          // table ready
  dq_write(0);
  __syncthreads();          // WT[0] ready

  for (int t = 0; t < NIT; ++t) {
    if (t + 1 < NIT) dq_load(t + 1);   // issue next-tile index loads early

    const char* wtb = (const char*)(&WT[t & 1][0]);
#pragma unroll
    for (int kk = 0; kk < 2; ++kk) {
      bf16x8 a[4], b[4];
#pragma unroll
      for (int mi = 0; mi < 4; ++mi)
        a[mi] = *reinterpret_cast<const bf16x8*>(
            xb + (size_t)mi * 16 * INF + t * BK + kk * 32);
      const unsigned int cb = ((unsigned)(kk * 64 + l4 * 16)) ^ bswz;
#pragma unroll
      for (int ni = 0; ni < 4; ++ni)
        b[ni] = *reinterpret_cast<const bf16x8*>(
            wtb + (wn * 64 + ni * 16 + l15) * 128 + cb);
#pragma unroll
      for (int mi = 0; mi < 4; ++mi)
#pragma unroll
        for (int ni = 0; ni < 4; ++ni)
          acc[mi][ni] = __builtin_amdgcn_mfma_f32_16x16x32_bf16(
              a[mi], b[ni], acc[mi][ni], 0, 0, 0);
    }

    if (t + 1 < NIT) dq_write((t + 1) & 1);  // dequant into the other buffer
    __syncthreads();
  }

  // ---- epilogue: split-K accumulate (out pre-zeroed by prep_kernel)
  float* ob = out + (size_t)(m0 + wm * 64 + l4 * 4) * MOUT + n0 + wn * 64 + l15;
#pragma unroll
  for (int mi = 0; mi < 4; ++mi)
#pragma unroll
    for (int ni = 0; ni < 4; ++ni)
#pragma unroll
      for (int r = 0; r < 4; ++r)
        atomicAdd(ob + (size_t)(mi * 16 + r) * MOUT + ni * 16, acc[mi][ni][r]);
}

extern "C" void kernel_launch(void* const* d_in, const int* in_sizes, int n_in,
                              void* d_out, int out_size, void* d_ws, size_t ws_size,
                              hipStream_t stream) {
  const float* inp = (const float*)d_in[0];
  const float* sw  = (const float*)d_in[1];
  const float* qs  = (const float*)d_in[2];
  const int*   qi  = (const int*)d_in[3];
  float* out = (float*)d_out;
  unsigned short* xs = (unsigned short*)d_ws;   // 256*4096 bf16 = 2 MB scratch

  prep_kernel<<<(BATCH * INF / 4) / 256, 256, 0, stream>>>(inp, sw, qs, xs, out);

  constexpr int GRID = (BATCH / BM) * (MOUT / BN) * KSPLIT;  // 2*32*4 = 256
  gemm_kernel<<<GRID, 256, 0, stream>>>(xs, qi, out);
}